// Round 1
// 680.397 us; speedup vs baseline: 1.1252x; 1.1252x over previous
//
#include <hip/hip_runtime.h>

#define SEQ 4096
#define NT  256
#define NA  64
#define NCKPT 16          // res checkpoints, every 256 steps
#define LOG2E 1.4426950408889634f

__device__ __forceinline__ float rdlanef(float v, int l) {
    return __int_as_float(__builtin_amdgcn_readlane(__float_as_int(v), l));
}

// ---------------------------------------------------------------------------
// Kernel 1: exact full-state chain. One wave per algo; lane owns columns
// 4L..4L+3 of res[256].
// v2: all per-step wave-uniform constants (col, tvk, kmem, prefetch row idx)
// are batch-loaded from LDS into lane-indexed VGPRs once per 64 steps and
// broadcast per step via v_readlane (no per-step ds_read / lgkmcnt on the
// critical path; prefetch address is pure SALU from an SGPR row index).
// ---------------------------------------------------------------------------
__global__ __launch_bounds__(64) void k_chain(
    const int* __restrict__ lx, const float* __restrict__ tm,
    const float* __restrict__ diff, const float* __restrict__ eff_p,
    const float* __restrict__ mem_p, const float* __restrict__ boost_p,
    float* __restrict__ gbuf, float* __restrict__ ckpt)
{
    __shared__ int   s_lx[SEQ + 8];
    __shared__ float s_tvk[SEQ + 8];   // tvk[t] = tm[lx[t-1]][lx[t]] * k[lx[t]]
    __shared__ float s_kmem[SEQ + 8];  // kmem[t] = mem * k[lx[t]]
    const int lane = threadIdx.x;
    const int a = blockIdx.x;

    for (int i = lane; i < SEQ; i += 64) s_lx[i] = lx[i];
    if (lane < 8) s_lx[SEQ + lane] = lx[SEQ - 1];
    __syncthreads();

    const float eff   = eff_p[a];
    const float mem   = mem_p[a];
    const float boost = boost_p[a];
    const float A = eff + boost;
    const float B = -2.0f * boost;

    // prologue: per-step uniform constants (gathers pipeline independently)
    for (int t = lane; t < SEQ; t += 64) {
        int c = s_lx[t];
        float k = LOG2E / diff[c];
        s_kmem[t] = mem * k;
        float tv = (t >= 1) ? tm[s_lx[t - 1] * NT + c] : 0.0f;
        s_tvk[t] = tv * k;
    }
    if (lane < 8) { s_kmem[SEQ + lane] = 0.0f; s_tvk[SEQ + lane] = 0.0f; }
    __syncthreads();

    float4 res = make_float4(0.0f, 0.0f, 0.0f, 0.0f);
    float g = eff;            // g_0  (sig_{-1} = 0)
    float gsave = g;

    // prefetch ring: tm row for step u, depth 8, coalesced float4 per lane
    float4 pf[8];
#pragma unroll
    for (int d = 0; d < 8; ++d)
        pf[d] = *(const float4*)(tm + s_lx[d] * NT + 4 * lane);

    for (int u0 = 0; u0 < SEQ; u0 += 64) {
        // batched LDS->VGPR: lane i holds step (u0+i)'s constants
        const int   vlx  = s_lx[u0 + 1 + lane];    // col of step u+1
        const float vtvk = s_tvk[u0 + 1 + lane];
        const float vkme = s_kmem[u0 + 1 + lane];
        const int   vpfl = s_lx[u0 + 8 + lane];    // prefetch row for step u+8

        for (int jo = 0; jo < 64; jo += 8) {
#pragma unroll
            for (int ji = 0; ji < 8; ++ji) {
                const int j = jo + ji;             // u = u0 + j
                // per-step uniform constants via readlane (SGPR, no lgkm)
                const int   coln  = __builtin_amdgcn_readlane(vlx, j);
                const float tvkn  = rdlanef(vtvk, j);
                const float kmemn = rdlanef(vkme, j);

                // capture g_u into lane j's gsave
                gsave = (lane == j) ? g : gsave;

                // probe res_{u-1}[coln] (pre-update) -> off-chain readlane
                const int o = coln >> 2, sub = coln & 3;
                float r01 = (sub & 1) ? res.y : res.x;
                float r23 = (sub & 1) ? res.w : res.z;
                float rsel = (sub & 2) ? r23 : r01;
                const float c1 = rdlanef(rsel, o) * kmemn;

                // res update (parallel with the sigmoid chain)
                const float4 row = pf[ji];
                res.x = fmaf(g, row.x, mem * res.x);
                res.y = fmaf(g, row.y, mem * res.y);
                res.z = fmaf(g, row.z, mem * res.z);
                res.w = fmaf(g, row.w, mem * res.w);

                // serial chain: g_{u+1}
                const float pb = fmaf(tvkn, g, c1);
                const float q  = __builtin_amdgcn_rcpf(
                                     __builtin_amdgcn_exp2f(pb) + 1.0f);
                g = fmaf(B, q, A);

                // prefetch tm row for step u+8 (SGPR base, fixed voffset)
                const int rowi = __builtin_amdgcn_readlane(vpfl, j);
                pf[ji] = *(const float4*)(tm + rowi * NT + 4 * lane);
            }
        }
        // batched g store: one coalesced store per 64 steps
        gbuf[a * SEQ + u0 + lane] = gsave;
        // res checkpoint every 256 steps (res after step u0+63)
        if ((u0 & 192) == 192)
            *(float4*)(ckpt + (a * NCKPT + (u0 >> 8)) * NT + 4 * lane) = res;
    }
}

// ---------------------------------------------------------------------------
// Kernel 2: regenerate sig for all (a, col, t) from g + checkpoints.
// Block = 1 wave = 64 columns; grid = algo x 4 col-groups x 16 chunks of 256.
// v2: per-element uniform values (g_i, prefetch row idx) batch-loaded into
// lane-indexed VGPRs per 64 steps + readlane broadcast, same as k_chain.
// 64x65 LDS tile transpose so HBM stores are contiguous along t.
// ---------------------------------------------------------------------------
__global__ __launch_bounds__(64) void k_out(
    const int* __restrict__ lx, const float* __restrict__ tm,
    const float* __restrict__ diff, const float* __restrict__ mem_p,
    const float* __restrict__ gbuf, const float* __restrict__ ckpt,
    float* __restrict__ out)
{
    __shared__ int   s_lx[256 + 8];
    __shared__ float s_g[256];
    __shared__ float s_tile[64 * 65];

    const int lane = threadIdx.x;
    const int b = blockIdx.x;
    const int a     = b >> 6;
    const int cg    = (b >> 4) & 3;
    const int chunk = b & 15;
    const int t0 = chunk << 8;

    for (int i = lane; i < 256; i += 64) {
        s_lx[i] = lx[t0 + i];
        s_g[i]  = gbuf[a * SEQ + t0 + i];
    }
    if (lane < 8) s_lx[256 + lane] = lx[t0 + 255];
    __syncthreads();

    const int c = (cg << 6) + lane;
    const float memv = mem_p[a];
    const float kc = LOG2E / diff[c];
    float res = (chunk == 0) ? 0.0f
                             : ckpt[(a * NCKPT + chunk - 1) * NT + c];

    // prefetch ring depth 8 for tm[lx[t0+i]][c]
    float pf[8];
#pragma unroll
    for (int d = 0; d < 8; ++d) pf[d] = tm[s_lx[d] * NT + c];

    const long rowbase = (long)(a * NT + (cg << 6)) * (SEQ + 1);
    for (int jb = 0; jb < 256; jb += 64) {
        const int   vpfl = s_lx[jb + 8 + lane];   // prefetch row for elem i+8
        const float vg   = s_g[jb + lane];        // g for elem jb+lane
        for (int j0 = 0; j0 < 64; j0 += 8) {
#pragma unroll
            for (int ji = 0; ji < 8; ++ji) {
                const int j2 = j0 + ji;           // i = jb + j2
                const float gi  = rdlanef(vg, j2);
                const float tmv = pf[ji];
                res = fmaf(memv, res, tmv * gi);
                const float q = __builtin_amdgcn_rcpf(
                                    __builtin_amdgcn_exp2f(res * kc) + 1.0f);
                s_tile[j2 * 65 + lane] = fmaf(-2.0f, q, 1.0f);
                const int rowi = __builtin_amdgcn_readlane(vpfl, j2);
                pf[ji] = tm[rowi * NT + c];       // SGPR base + voffset
            }
        }
        __syncthreads();
        const int tbase = t0 + jb + 1;
#pragma unroll 8
        for (int r = 0; r < 64; ++r) {
            out[rowbase + (long)r * (SEQ + 1) + tbase + lane] =
                s_tile[lane * 65 + r];
        }
        __syncthreads();
    }
    if (chunk == 0) out[rowbase + (long)lane * (SEQ + 1)] = 0.0f;
}

extern "C" void kernel_launch(void* const* d_in, const int* in_sizes, int n_in,
                              void* d_out, int out_size, void* d_ws, size_t ws_size,
                              hipStream_t stream)
{
    const int*   lx    = (const int*)d_in[0];
    const float* tm    = (const float*)d_in[1];
    const float* diff  = (const float*)d_in[2];
    const float* eff   = (const float*)d_in[3];
    const float* memp  = (const float*)d_in[4];
    const float* boost = (const float*)d_in[5];
    float* gbuf = (float*)d_ws;                          // 64*4096*4 = 1 MB
    float* ckpt = gbuf + NA * SEQ;                       // 64*16*256*4 = 1 MB
    float* out  = (float*)d_out;

    k_chain<<<NA, 64, 0, stream>>>(lx, tm, diff, eff, memp, boost, gbuf, ckpt);
    k_out<<<NA * 4 * NCKPT, 64, 0, stream>>>(lx, tm, diff, memp, gbuf, ckpt, out);
}

// Round 2
// 591.598 us; speedup vs baseline: 1.2941x; 1.1501x over previous
//
#include <hip/hip_runtime.h>

#define SEQ 4096
#define NT  256
#define NA  64
#define NCKPT 16          // res checkpoints, every 256 steps
#define LOG2E 1.4426950408889634f

__device__ __forceinline__ float rdlanef(float v, int l) {
    return __int_as_float(__builtin_amdgcn_readlane(__float_as_int(v), l));
}

// ---------------------------------------------------------------------------
// Kernel 1: exact full-state chain. One wave per algo.
// v3: block-factored serial chain. For each 64-step block starting at B,
// lane j owns step u=B+j and accumulates
//   D_j = k_j * ( mem^{j+1} * res_{B-1}[c_{B+j+1}]
//                 + sum_{i<=j} mem^{j-i} * tm[c_{B+i}][c_{B+j+1}] * g_{B+i} )
// via D = fma(mem, D, T'[i]*g) where T'[i][j] = k_j*tm[c_{B+i}][c_{B+j+1}]
// is gathered per block (off-chain). pb_j = readlane(D, j) feeds the sigmoid
// chain directly. The full res state is updated once per block as a batched
// weighted sum (identical algebraic nesting), only to serve checkpoints and
// the next block's D init. Serial loop: 7 VALU + 1 readlane per step.
// ---------------------------------------------------------------------------
__global__ __launch_bounds__(64) void k_chain(
    const int* __restrict__ lx, const float* __restrict__ tm,
    const float* __restrict__ diff, const float* __restrict__ eff_p,
    const float* __restrict__ mem_p, const float* __restrict__ boost_p,
    float* __restrict__ gbuf, float* __restrict__ ckpt)
{
    __shared__ int   s_lx[SEQ + 8];
    __shared__ float s_res[NT];
    const int lane = threadIdx.x;
    const int a = blockIdx.x;

    for (int i = lane; i < SEQ; i += 64) s_lx[i] = lx[i];
    if (lane < 8) s_lx[SEQ + lane] = lx[SEQ - 1];
    *(float4*)&s_res[4 * lane] = make_float4(0.f, 0.f, 0.f, 0.f);
    __syncthreads();

    const float eff   = eff_p[a];
    const float mem   = mem_p[a];
    const float boost = boost_p[a];
    const float A  = eff + boost;
    const float Bc = -2.0f * boost;

    // mpow = mem^(63-lane); m64 = mem^64 (binary exponentiation, per lane)
    float mpow = 1.0f, bb = mem;
    {
        const int n = 63 - lane;
#pragma unroll
        for (int k = 0; k < 6; ++k) { if (n & (1 << k)) mpow *= bb; bb *= bb; }
    }
    const float m64 = bb;

    float4 res = make_float4(0.0f, 0.0f, 0.0f, 0.0f);
    float g = eff;            // g_0  (sig_{-1} = 0)
    float garr = g;
    float T[64];

    // ---- prep block 0 ----
    int   vrow  = s_lx[lane];          // row c_{B+lane}
    int   vcol  = s_lx[1 + lane];      // target column c_{B+lane+1}
    float klane = LOG2E / diff[vcol];
    float D = 0.0f;                    // k * res_{-1}[c] = 0
#pragma unroll
    for (int i = 0; i < 64; ++i) {
        const int r = __builtin_amdgcn_readlane(vrow, i);
        T[i] = klane * tm[r * NT + vcol];
    }

    for (int B = 0; B < SEQ; B += 64) {
        // ---- serial chain: 64 steps, fully unrolled ----
#pragma unroll
        for (int j = 0; j < 64; ++j) {
            garr = (lane == j) ? g : garr;      // capture g_{B+j}
            const float tg = T[j] * g;
            D = fmaf(mem, D, tg);
            const float pb = rdlanef(D, j);
            const float q  = __builtin_amdgcn_rcpf(
                                 __builtin_amdgcn_exp2f(pb) + 1.0f);
            g = fmaf(Bc, q, A);
        }
        gbuf[a * SEQ + B + lane] = garr;

        const int Bn = B + 64;
        const bool last = (Bn >= SEQ);

        // ---- next-block constants + T-gather (issued early; overlaps the
        //      res-update latency below; depends only on lx) ----
        int vrow_n = vrow, vcol_n = vcol; float klane_n = klane;
        if (!last) {
            vrow_n  = s_lx[Bn + lane];
            vcol_n  = s_lx[Bn + 1 + lane];
            klane_n = LOG2E / diff[vcol_n];
#pragma unroll
            for (int i = 0; i < 64; ++i) {
                const int r = __builtin_amdgcn_readlane(vrow_n, i);
                T[i] = klane_n * tm[r * NT + vcol_n];
            }
        }

        // ---- batched res update for this block ----
        // res = mem^64 * res + sum_i mem^(63-i) * g_{B+i} * tm[c_{B+i}][:]
        const float w = garr * mpow;
        res.x *= m64; res.y *= m64; res.z *= m64; res.w *= m64;
        float4 pf[16];
#pragma unroll
        for (int d = 0; d < 16; ++d) {
            const int r = __builtin_amdgcn_readlane(vrow, d);
            pf[d] = *(const float4*)(tm + r * NT + 4 * lane);
        }
#pragma unroll
        for (int i = 0; i < 64; ++i) {
            const float sw = rdlanef(w, i);
            const float4 row = pf[i & 15];
            res.x = fmaf(sw, row.x, res.x);
            res.y = fmaf(sw, row.y, res.y);
            res.z = fmaf(sw, row.z, res.z);
            res.w = fmaf(sw, row.w, res.w);
            if (i < 48) {
                const int r = __builtin_amdgcn_readlane(vrow, i + 16);
                pf[i & 15] = *(const float4*)(tm + r * NT + 4 * lane);
            }
        }
        if ((Bn & 255) == 0)
            *(float4*)(ckpt + (a * NCKPT + (B >> 8)) * NT + 4 * lane) = res;

        if (!last) {
            // publish res_{Bn-1} and init next block's D
            __syncthreads();
            *(float4*)&s_res[4 * lane] = res;
            __syncthreads();
            const float R = s_res[vcol_n];
            D = klane_n * R;
            vrow = vrow_n; vcol = vcol_n; klane = klane_n;
        }
    }
}

// ---------------------------------------------------------------------------
// Kernel 2: regenerate sig for all (a, col, t) from g + checkpoints.
// Block = 1 wave = 64 columns; grid = algo x 4 col-groups x 16 chunks of 256.
// Per-element uniform values (g_i, prefetch row idx) batch-loaded into
// lane-indexed VGPRs per 64 steps + readlane broadcast.
// 64x65 LDS tile transpose so HBM stores are contiguous along t.
// ---------------------------------------------------------------------------
__global__ __launch_bounds__(64) void k_out(
    const int* __restrict__ lx, const float* __restrict__ tm,
    const float* __restrict__ diff, const float* __restrict__ mem_p,
    const float* __restrict__ gbuf, const float* __restrict__ ckpt,
    float* __restrict__ out)
{
    __shared__ int   s_lx[256 + 8];
    __shared__ float s_g[256];
    __shared__ float s_tile[64 * 65];

    const int lane = threadIdx.x;
    const int b = blockIdx.x;
    const int a     = b >> 6;
    const int cg    = (b >> 4) & 3;
    const int chunk = b & 15;
    const int t0 = chunk << 8;

    for (int i = lane; i < 256; i += 64) {
        s_lx[i] = lx[t0 + i];
        s_g[i]  = gbuf[a * SEQ + t0 + i];
    }
    if (lane < 8) s_lx[256 + lane] = lx[t0 + 255];
    __syncthreads();

    const int c = (cg << 6) + lane;
    const float memv = mem_p[a];
    const float kc = LOG2E / diff[c];
    float res = (chunk == 0) ? 0.0f
                             : ckpt[(a * NCKPT + chunk - 1) * NT + c];

    // prefetch ring depth 8 for tm[lx[t0+i]][c]
    float pf[8];
#pragma unroll
    for (int d = 0; d < 8; ++d) pf[d] = tm[s_lx[d] * NT + c];

    const long rowbase = (long)(a * NT + (cg << 6)) * (SEQ + 1);
    for (int jb = 0; jb < 256; jb += 64) {
        const int   vpfl = s_lx[jb + 8 + lane];   // prefetch row for elem i+8
        const float vg   = s_g[jb + lane];        // g for elem jb+lane
        for (int j0 = 0; j0 < 64; j0 += 8) {
#pragma unroll
            for (int ji = 0; ji < 8; ++ji) {
                const int j2 = j0 + ji;           // i = jb + j2
                const float gi  = rdlanef(vg, j2);
                const float tmv = pf[ji];
                res = fmaf(memv, res, tmv * gi);
                const float q = __builtin_amdgcn_rcpf(
                                    __builtin_amdgcn_exp2f(res * kc) + 1.0f);
                s_tile[j2 * 65 + lane] = fmaf(-2.0f, q, 1.0f);
                const int rowi = __builtin_amdgcn_readlane(vpfl, j2);
                pf[ji] = tm[rowi * NT + c];       // SGPR base + voffset
            }
        }
        __syncthreads();
        const int tbase = t0 + jb + 1;
#pragma unroll 8
        for (int r = 0; r < 64; ++r) {
            out[rowbase + (long)r * (SEQ + 1) + tbase + lane] =
                s_tile[lane * 65 + r];
        }
        __syncthreads();
    }
    if (chunk == 0) out[rowbase + (long)lane * (SEQ + 1)] = 0.0f;
}

extern "C" void kernel_launch(void* const* d_in, const int* in_sizes, int n_in,
                              void* d_out, int out_size, void* d_ws, size_t ws_size,
                              hipStream_t stream)
{
    const int*   lx    = (const int*)d_in[0];
    const float* tm    = (const float*)d_in[1];
    const float* diff  = (const float*)d_in[2];
    const float* eff   = (const float*)d_in[3];
    const float* memp  = (const float*)d_in[4];
    const float* boost = (const float*)d_in[5];
    float* gbuf = (float*)d_ws;                          // 64*4096*4 = 1 MB
    float* ckpt = gbuf + NA * SEQ;                       // 64*16*256*4 = 1 MB
    float* out  = (float*)d_out;

    k_chain<<<NA, 64, 0, stream>>>(lx, tm, diff, eff, memp, boost, gbuf, ckpt);
    k_out<<<NA * 4 * NCKPT, 64, 0, stream>>>(lx, tm, diff, memp, gbuf, ckpt, out);
}